// Round 3
// baseline (72.810 us; speedup 1.0000x reference)
//
#include <hip/hip_runtime.h>

// Fourier head: B=512, P=1024, K=64.
// out[b,p] = a0/(2P) + sum_k pa[b,k]*cos(c*x[b,p]*k) + pb[b,k]*sin(c*x[b,p]*k)
// pa = x @ a, pb = x @ b, c = 2*pi/P.
//
// Dtype model (R0-R2 triangulation): inputs f32, OUTPUT f32.
//  - R0 stub zeros -> err 5.1875 == max|ref|       (any output dtype)
//  - R1 bf16-read of f32 inputs -> NaN             (inputs are f32)
//  - R2 bf16-packed writes -> err 6.69 > max|ref|  (output is f32; harness read
//    our bf16 pairs as f32 words)
// Compute in f32 throughout.

constexpr int PN = 1024;
constexpr int KN = 64;
constexpr int ROWS = 2;   // batch rows per block; grid = 512/ROWS = 256 = #CUs.
                          // Halves aggregate a/b L2 streaming (256MB -> 128MB).

__global__ __launch_bounds__(256) void fourier_fused(
    const float* __restrict__ x,
    const float* __restrict__ a,
    const float* __restrict__ bco,
    const float* __restrict__ a0,
    float* __restrict__ out)
{
    __shared__ float xs[ROWS][PN];           // 8 KB
    __shared__ float red[2][ROWS][16][KN];   // 16 KB
    __shared__ float spa[ROWS][KN];          // 512 B
    __shared__ float spb[ROWS][KN];          // 512 B

    const int t = threadIdx.x;
    const int b0 = blockIdx.x * ROWS;

    // ---- Stage A: ROWS x-rows -> LDS (float4, 16B/lane coalesced) ----
    #pragma unroll
    for (int r = 0; r < ROWS; ++r) {
        float4 v = ((const float4*)(x + (size_t)(b0 + r) * PN))[t];
        xs[r][4 * t + 0] = v.x;
        xs[r][4 * t + 1] = v.y;
        xs[r][4 * t + 2] = v.z;
        xs[r][4 * t + 3] = v.w;
    }
    __syncthreads();

    // ---- Stage B: pa[r][k] = sum_p xs[r][p]*a[p,k]; pb likewise ----
    // 256 threads = 16 k-groups (float4 along K) x 16 p-groups.
    // Each a/b float4 is reused across ROWS rows (16 FMA per 32 loaded bytes).
    {
        const int kg = t & 15;               // k = 4*kg + j
        const int pg = t >> 4;               // p = pg + 16*i
        float sa[ROWS][4] = {};
        float sb[ROWS][4] = {};
        #pragma unroll 4
        for (int i = 0; i < 64; ++i) {
            const int p = pg + 16 * i;
            const float4 av = *(const float4*)(a   + p * KN + 4 * kg);
            const float4 bv = *(const float4*)(bco + p * KN + 4 * kg);
            #pragma unroll
            for (int r = 0; r < ROWS; ++r) {
                const float xv = xs[r][p];
                sa[r][0] = fmaf(xv, av.x, sa[r][0]);
                sa[r][1] = fmaf(xv, av.y, sa[r][1]);
                sa[r][2] = fmaf(xv, av.z, sa[r][2]);
                sa[r][3] = fmaf(xv, av.w, sa[r][3]);
                sb[r][0] = fmaf(xv, bv.x, sb[r][0]);
                sb[r][1] = fmaf(xv, bv.y, sb[r][1]);
                sb[r][2] = fmaf(xv, bv.z, sb[r][2]);
                sb[r][3] = fmaf(xv, bv.w, sb[r][3]);
            }
        }
        #pragma unroll
        for (int r = 0; r < ROWS; ++r) {
            #pragma unroll
            for (int j = 0; j < 4; ++j) {
                red[0][r][pg][4 * kg + j] = sa[r][j];
                red[1][r][pg][4 * kg + j] = sb[r][j];
            }
        }
    }
    __syncthreads();

    // ---- Reduce over the 16 p-groups: 2 * ROWS * 64 = 256 sums, 1/thread ----
    {
        const int which = t >> 7;            // 0: pa, 1: pb
        const int r = (t >> 6) & (ROWS - 1);
        const int k = t & 63;
        float s = 0.f;
        #pragma unroll
        for (int pg = 0; pg < 16; ++pg) s += red[which][r][pg][k];
        if (which == 0) spa[r][k] = s; else spb[r][k] = s;
    }
    __syncthreads();

    // ---- Stage C: per row, 4 points/thread via angle-addition recurrence ----
    const float c0 = a0[0] * (1.0f / (2.0f * (float)PN));
    const float tp = (float)(6.283185307179586 / (double)PN);  // 2*pi/P

    #pragma unroll
    for (int r = 0; r < ROWS; ++r) {
        float cth[4], sth[4], cc[4], ss[4], acc[4];
        const float pa0 = spa[r][0];
        #pragma unroll
        for (int j = 0; j < 4; ++j) {
            const float th = tp * xs[r][4 * t + j];
            __sincosf(th, &sth[j], &cth[j]);
            cc[j] = cth[j];                  // cos(theta)
            ss[j] = sth[j];                  // sin(theta)
            acc[j] = c0 + pa0;               // k=0: cos=1, sin=0
        }
        for (int k = 1; k < KN; ++k) {
            const float pak = spa[r][k];     // wave-uniform LDS broadcast
            const float pbk = spb[r][k];
            #pragma unroll
            for (int j = 0; j < 4; ++j) {
                acc[j] = fmaf(pak, cc[j], acc[j]);
                acc[j] = fmaf(pbk, ss[j], acc[j]);
                const float nc = fmaf(-ss[j], sth[j], cc[j] * cth[j]);
                const float ns = fmaf( cc[j], sth[j], ss[j] * cth[j]);
                cc[j] = nc;
                ss[j] = ns;
            }
        }
        float4 o;
        o.x = acc[0]; o.y = acc[1]; o.z = acc[2]; o.w = acc[3];
        ((float4*)(out + (size_t)(b0 + r) * PN))[t] = o;
    }
}

extern "C" void kernel_launch(void* const* d_in, const int* in_sizes, int n_in,
                              void* d_out, int out_size, void* d_ws, size_t ws_size,
                              hipStream_t stream) {
    const float* x  = (const float*)d_in[0];
    const float* a  = (const float*)d_in[1];
    const float* b  = (const float*)d_in[2];
    const float* a0 = (const float*)d_in[3];
    float* out = (float*)d_out;

    const int nblocks = (out_size / PN) / ROWS;  // = 512/2 = 256
    fourier_fused<<<dim3(nblocks), dim3(256), 0, stream>>>(x, a, b, a0, out);
}

// Round 4
// 72.056 us; speedup vs baseline: 1.0105x; 1.0105x over previous
//
#include <hip/hip_runtime.h>

// Fourier head: B=512, P=1024, K=64.
// out[b,p] = a0/(2P) + sum_k pa[b,k]*cos(c*x[b,p]*k) + pb[b,k]*sin(c*x[b,p]*k)
// pa = x @ a, pb = x @ b, c = 2*pi/P.
//
// Dtypes (R0-R2 triangulation): inputs f32, output f32. Compute f32.
// R3: passed, absmax 0.0156, dur_us 72.8. rocprof: top-5 dispatches are the
// harness's 256MB d_ws re-poison fills (~40us @ 84% HBM peak) -> our kernel
// is <40us (model: ~8us). dur_us is dominated by ~65us harness overhead.
// R4: Chebyshev recurrence (4 FMA/k vs 6 ops/k) + interleaved pa/pb LDS.

constexpr int PN = 1024;
constexpr int KN = 64;
constexpr int ROWS = 2;   // rows/block; grid = 256 = #CUs -> stage B reads
                          // a+b (512KB) once per block: 128MB L2 aggregate.

__global__ __launch_bounds__(256) void fourier_fused(
    const float* __restrict__ x,
    const float* __restrict__ a,
    const float* __restrict__ bco,
    const float* __restrict__ a0,
    float* __restrict__ out)
{
    __shared__ float xs[ROWS][PN];           // 8 KB
    __shared__ float red[2][ROWS][16][KN];   // 16 KB
    __shared__ float spab[ROWS][2 * KN];     // 1 KB, pa/pb interleaved

    const int t = threadIdx.x;
    const int b0 = blockIdx.x * ROWS;

    // ---- Stage A: ROWS x-rows -> LDS (float4, 16B/lane coalesced) ----
    #pragma unroll
    for (int r = 0; r < ROWS; ++r) {
        float4 v = ((const float4*)(x + (size_t)(b0 + r) * PN))[t];
        xs[r][4 * t + 0] = v.x;
        xs[r][4 * t + 1] = v.y;
        xs[r][4 * t + 2] = v.z;
        xs[r][4 * t + 3] = v.w;
    }
    __syncthreads();

    // ---- Stage B: pa[r][k] = sum_p xs[r][p]*a[p,k]; pb likewise ----
    // 256 threads = 16 k-groups (float4 along K) x 16 p-groups.
    // One wave's loads cover 1KB contiguous (p in [16i,16i+4), full K rows).
    {
        const int kg = t & 15;               // k = 4*kg + j
        const int pg = t >> 4;               // p = pg + 16*i
        float sa[ROWS][4] = {};
        float sb[ROWS][4] = {};
        #pragma unroll 4
        for (int i = 0; i < 64; ++i) {
            const int p = pg + 16 * i;
            const float4 av = *(const float4*)(a   + p * KN + 4 * kg);
            const float4 bv = *(const float4*)(bco + p * KN + 4 * kg);
            #pragma unroll
            for (int r = 0; r < ROWS; ++r) {
                const float xv = xs[r][p];
                sa[r][0] = fmaf(xv, av.x, sa[r][0]);
                sa[r][1] = fmaf(xv, av.y, sa[r][1]);
                sa[r][2] = fmaf(xv, av.z, sa[r][2]);
                sa[r][3] = fmaf(xv, av.w, sa[r][3]);
                sb[r][0] = fmaf(xv, bv.x, sb[r][0]);
                sb[r][1] = fmaf(xv, bv.y, sb[r][1]);
                sb[r][2] = fmaf(xv, bv.z, sb[r][2]);
                sb[r][3] = fmaf(xv, bv.w, sb[r][3]);
            }
        }
        #pragma unroll
        for (int r = 0; r < ROWS; ++r) {
            #pragma unroll
            for (int j = 0; j < 4; ++j) {
                red[0][r][pg][4 * kg + j] = sa[r][j];
                red[1][r][pg][4 * kg + j] = sb[r][j];
            }
        }
    }
    __syncthreads();

    // ---- Reduce 16 p-groups: 2*ROWS*64 = 256 sums, one per thread ----
    {
        const int which = t >> 7;            // 0: pa, 1: pb
        const int r = (t >> 6) & (ROWS - 1);
        const int k = t & 63;
        float s = 0.f;
        #pragma unroll
        for (int pg = 0; pg < 16; ++pg) s += red[which][r][pg][k];
        spab[r][2 * k + which] = s;          // stride-2: 2-way bank alias, free
    }
    __syncthreads();

    // ---- Stage C: Chebyshev recurrence, 4 points/thread/row ----
    // c_k = 2c1*c_{k-1} - c_{k-2}; s_k likewise. 4 FMA per k per point.
    const float c0 = a0[0] * (1.0f / (2.0f * (float)PN));
    const float tp = (float)(6.283185307179586 / (double)PN);  // 2*pi/P

    #pragma unroll
    for (int r = 0; r < ROWS; ++r) {
        float cm1[4], sm1[4], cm2[4], sm2[4], t2[4], acc[4];
        const float pa0 = spab[r][0];
        const float pa1 = spab[r][2];
        const float pb1 = spab[r][3];
        #pragma unroll
        for (int j = 0; j < 4; ++j) {
            const float th = tp * xs[r][4 * t + j];
            float c1, s1;
            __sincosf(th, &s1, &c1);
            t2[j]  = c1 + c1;
            cm2[j] = 1.f; sm2[j] = 0.f;      // k=0
            cm1[j] = c1;  sm1[j] = s1;       // k=1
            acc[j] = fmaf(pa1, c1, fmaf(pb1, s1, c0 + pa0));
        }
        #pragma unroll 8
        for (int k = 2; k < KN; ++k) {
            const float2 pk = *(const float2*)&spab[r][2 * k];  // ds_read_b64
            #pragma unroll
            for (int j = 0; j < 4; ++j) {
                const float ck = fmaf(t2[j], cm1[j], -cm2[j]);
                const float sk = fmaf(t2[j], sm1[j], -sm2[j]);
                acc[j] = fmaf(pk.x, ck, acc[j]);
                acc[j] = fmaf(pk.y, sk, acc[j]);
                cm2[j] = cm1[j]; cm1[j] = ck;
                sm2[j] = sm1[j]; sm1[j] = sk;
            }
        }
        float4 o;
        o.x = acc[0]; o.y = acc[1]; o.z = acc[2]; o.w = acc[3];
        ((float4*)(out + (size_t)(b0 + r) * PN))[t] = o;
    }
}

extern "C" void kernel_launch(void* const* d_in, const int* in_sizes, int n_in,
                              void* d_out, int out_size, void* d_ws, size_t ws_size,
                              hipStream_t stream) {
    const float* x  = (const float*)d_in[0];
    const float* a  = (const float*)d_in[1];
    const float* b  = (const float*)d_in[2];
    const float* a0 = (const float*)d_in[3];
    float* out = (float*)d_out;

    const int nblocks = (out_size / PN) / ROWS;  // = 256
    fourier_fused<<<dim3(nblocks), dim3(256), 0, stream>>>(x, a, b, a0, out);
}